// Round 13
// baseline (186.232 us; speedup 1.0000x reference)
//
#include <hip/hip_runtime.h>
#include <hip/hip_bf16.h>

#define Hh 50

typedef __attribute__((ext_vector_type(8))) short bf16x8;
typedef __attribute__((ext_vector_type(4))) float f32x4;

static __device__ __forceinline__ short b16(float x) {
    return __builtin_bit_cast(short, __float2bfloat16(x));
}
// convert 8 contiguous f32 to a bf16x8 MFMA fragment
static __device__ __forceinline__ bf16x8 cvt8(const float* p) {
    f32x4 a = *(const f32x4*)p;
    f32x4 b = *(const f32x4*)(p + 4);
    bf16x8 r;
    r[0] = b16(a[0]); r[1] = b16(a[1]); r[2] = b16(a[2]); r[3] = b16(a[3]);
    r[4] = b16(b[0]); r[5] = b16(b[1]); r[6] = b16(b[2]); r[7] = b16(b[3]);
    return r;
}

// -------- Kernel 0: pack wh_w into 16x16x32 B-fragment order --------
// whpk[((p*8+ks)*64+l)*8+j] = bf16(wh_w[p*16+(l&15)][ks*32+(l>>4)*8+j])
__global__ __launch_bounds__(256) void k_prep(const float* __restrict__ w,
                                              short* __restrict__ o) {
    int t = (int)blockIdx.x * 256 + threadIdx.x;   // 0..8191
    int p  = t >> 9;
    int ks = (t >> 6) & 7;
    int l  = t & 63;
    int col = p * 16 + (l & 15);
    int k   = ks * 32 + (l >> 4) * 8;
    bf16x8 v = cvt8(w + (size_t)col * 256 + k);
    *(bf16x8*)(o + (size_t)t * 8) = v;
}

// ---------------- Kernel 1: wc_out[4096][256] (f32) = cur @ wc_w^T + wc_b ----------------
__global__ __launch_bounds__(64) void k_wc(const float* __restrict__ cur,
                                           const float* __restrict__ wcw,
                                           const float* __restrict__ wcb,
                                           float* __restrict__ out) {
    int l = threadIdx.x;
    int m0 = (int)(blockIdx.x >> 2) * 16;
    int ntb = (int)(blockIdx.x & 3) * 4;
    int lk = (l >> 4) * 8;

    bf16x8 Af[8];
#pragma unroll
    for (int k = 0; k < 8; k++)
        Af[k] = cvt8(cur + (size_t)(m0 + (l & 15)) * 256 + k * 32 + lk);

#pragma unroll
    for (int nt = 0; nt < 4; nt++) {
        int col = (ntb + nt) * 16 + (l & 15);
        f32x4 a = {0.f, 0.f, 0.f, 0.f};
#pragma unroll
        for (int k = 0; k < 8; k++) {
            bf16x8 Bf = cvt8(wcw + (size_t)col * 256 + k * 32 + lk);
            a = __builtin_amdgcn_mfma_f32_16x16x32_bf16(Af[k], Bf, a, 0, 0, 0);
        }
        float bias = wcb[col];
        int row = m0 + (l >> 4) * 4;
#pragma unroll
        for (int r = 0; r < 4; r++)
            out[(size_t)(row + r) * 256 + col] = a[r] + bias;
    }
}

// ---------------- Kernel 2 (twin): fused wh GEMM + sigmoid + qt dot + alpha*hist --------
// V==0: real. 16 independent MFMA chains (acc[4m][4nt]), SINGLE-buffered A/B per ks
//       (~52 arch VGPR transient; acc -> AGPR) so nothing can spill.
// V==1: ablation — B loaded ONCE before the loop and reused for every ks (math wrong,
//       everything live). Removes the per-ks global B-load dependency. Output -> dummy.
template <int V>
__global__ __launch_bounds__(256, 4)
void k_main(const float* __restrict__ hist,
            const float* __restrict__ wc_ws,
            const short* __restrict__ whpk,
            const float* __restrict__ whb,
            const float* __restrict__ qtw,
            const float* __restrict__ qtb,
            float* __restrict__ hsum_ws) {
    __shared__ __align__(16) char histA[64 * 512];   // swizzled bf16 [row][256]
    __shared__ float wcrow[256];                     // wc_out[b,s,:] + wh_b
    __shared__ float qtl[256];
    __shared__ float alphaP[4][64];
    __shared__ float alphaF[64];

    int tid = threadIdx.x;
    int l = tid & 63;
    int w = tid >> 6;
    int b = (int)(blockIdx.x >> 9);
    int s = (int)(blockIdx.x & 511);

    // stage 50 hist rows (f32 -> bf16) into swizzled LDS
    for (int c = tid; c < 1600; c += 256) {
        int r = c >> 5, g = c & 31;
        bf16x8 v = cvt8(hist + ((size_t)(b * Hh + r) * 512 + s) * 256 + g * 8);
        *(bf16x8*)(&histA[r * 512 + ((g ^ (r & 15)) << 4)]) = v;
    }
    // zero pad rows 50..63
    if (tid < 448) {
        int r = 50 + (tid >> 5), g = tid & 31;
        *(f32x4*)(&histA[r * 512 + ((g ^ (r & 15)) << 4)]) = (f32x4){0.f, 0.f, 0.f, 0.f};
    }
    wcrow[tid] = wc_ws[(size_t)(b * 512 + s) * 256 + tid] + whb[tid];
    qtl[tid] = qtw[tid];
    __syncthreads();

    f32x4 acc[4][4];
#pragma unroll
    for (int m = 0; m < 4; m++)
#pragma unroll
        for (int nt = 0; nt < 4; nt++)
            acc[m][nt] = (f32x4){0.f, 0.f, 0.f, 0.f};

    bf16x8 Bfix[4];
    if (V == 1) {
#pragma unroll
        for (int nt = 0; nt < 4; nt++) {
            int p = w * 4 + nt;
            Bfix[nt] = *(const bf16x8*)(whpk + ((size_t)((p * 8) * 64 + l)) * 8);
        }
    }

#pragma unroll
    for (int ks = 0; ks < 8; ks++) {
        bf16x8 Bf[4];
        if (V == 0) {
#pragma unroll
            for (int nt = 0; nt < 4; nt++) {
                int p = w * 4 + nt;
                Bf[nt] = *(const bf16x8*)(whpk + ((size_t)((p * 8 + ks) * 64 + l)) * 8);
            }
        }
        bf16x8 Am[4];
#pragma unroll
        for (int m = 0; m < 4; m++) {
            int rA = m * 16 + (l & 15);
            int g = ks * 4 + (l >> 4);
            Am[m] = *(const bf16x8*)(&histA[rA * 512 + ((g ^ (rA & 15)) << 4)]);
        }
#pragma unroll
        for (int m = 0; m < 4; m++)
#pragma unroll
            for (int nt = 0; nt < 4; nt++)
                acc[m][nt] = __builtin_amdgcn_mfma_f32_16x16x32_bf16(
                    Am[m], (V == 0) ? Bf[nt] : Bfix[nt], acc[m][nt], 0, 0, 0);
    }

    // ---- epilogue: sigmoid + qt, per-lane partial over this wave's 64 cols ----
    float pal[4][4];
#pragma unroll
    for (int m = 0; m < 4; m++)
#pragma unroll
        for (int r = 0; r < 4; r++) pal[m][r] = 0.f;

#pragma unroll
    for (int m = 0; m < 4; m++) {
#pragma unroll
        for (int nt = 0; nt < 4; nt++) {
            int col = w * 64 + nt * 16 + (l & 15);
            float qv = qtl[col], wb = wcrow[col];
#pragma unroll
            for (int r = 0; r < 4; r++) {
                float v = acc[m][nt][r] + wb;
                pal[m][r] += qv * __builtin_amdgcn_rcpf(1.0f + __expf(-v));
            }
        }
    }

    // reduce over the 16 lanes holding the 16 cols of each tile
#pragma unroll
    for (int m = 0; m < 4; m++) {
#pragma unroll
        for (int r = 0; r < 4; r++) {
            float v = pal[m][r];
            v += __shfl_xor(v, 1);
            v += __shfl_xor(v, 2);
            v += __shfl_xor(v, 4);
            v += __shfl_xor(v, 8);
            if ((l & 15) == 0)
                alphaP[w][m * 16 + (l >> 4) * 4 + r] = v;
        }
    }
    __syncthreads();
    if (tid < Hh)
        alphaF[tid] = qtb[0] + alphaP[0][tid] + alphaP[1][tid] + alphaP[2][tid] + alphaP[3][tid];
    __syncthreads();

    // history_sum = sum_h alpha[h] * hist[h], from LDS; one f32 column/thread
    {
        int d = tid;
        float a = 0.f;
#pragma unroll 2
        for (int h = 0; h < Hh; h++) {
            int g = (d >> 3) ^ (h & 15);
            unsigned short u = *(const unsigned short*)(&histA[h * 512 + (g << 4) + (d & 7) * 2]);
            unsigned int x = ((unsigned int)u) << 16;
            a += alphaF[h] * __builtin_bit_cast(float, x);
        }
        hsum_ws[(size_t)(b * 512 + s) * 256 + d] = a;
    }
}

// ---------------- Kernel 3: out[4096][128] (f32) = [cur, hsum] @ wf_w^T + wf_b ----------------
__global__ __launch_bounds__(64) void k_wf(const float* __restrict__ cur,
                                           const float* __restrict__ hsum,
                                           const float* __restrict__ wfw,
                                           const float* __restrict__ wfb,
                                           float* __restrict__ out) {
    int l = threadIdx.x;
    int m0 = (int)(blockIdx.x >> 1) * 16;
    int ntb = (int)(blockIdx.x & 1) * 4;
    int lk = (l >> 4) * 8;

    f32x4 acc[4];
#pragma unroll
    for (int nt = 0; nt < 4; nt++) acc[nt] = (f32x4){0.f, 0.f, 0.f, 0.f};

#pragma unroll
    for (int k = 0; k < 16; k++) {
        int row = m0 + (l & 15);
        bf16x8 Af;
        if (k < 8)
            Af = cvt8(cur + (size_t)row * 256 + k * 32 + lk);
        else
            Af = cvt8(hsum + (size_t)row * 256 + (k - 8) * 32 + lk);
#pragma unroll
        for (int nt = 0; nt < 4; nt++) {
            int col = (ntb + nt) * 16 + (l & 15);
            bf16x8 Bf = cvt8(wfw + (size_t)col * 512 + k * 32 + lk);
            acc[nt] = __builtin_amdgcn_mfma_f32_16x16x32_bf16(Af, Bf, acc[nt], 0, 0, 0);
        }
    }
#pragma unroll
    for (int nt = 0; nt < 4; nt++) {
        int col = (ntb + nt) * 16 + (l & 15);
        float bias = wfb[col];
        int row = m0 + (l >> 4) * 4;
#pragma unroll
        for (int r = 0; r < 4; r++)
            out[(size_t)(row + r) * 128 + col] = acc[nt][r] + bias;
    }
}

extern "C" void kernel_launch(void* const* d_in, const int* in_sizes, int n_in,
                              void* d_out, int out_size, void* d_ws, size_t ws_size,
                              hipStream_t stream) {
    const float* hist = (const float*)d_in[0];
    const float* cur  = (const float*)d_in[1];
    const float* wc_w = (const float*)d_in[2];
    const float* wc_b = (const float*)d_in[3];
    const float* wh_w = (const float*)d_in[4];
    const float* wh_b = (const float*)d_in[5];
    const float* qt_w = (const float*)d_in[6];
    const float* qt_b = (const float*)d_in[7];
    const float* wf_w = (const float*)d_in[8];
    const float* wf_b = (const float*)d_in[9];

    float* wc_ws = (float*)d_ws;                                   // 4 MB
    float* hsum  = (float*)((char*)d_ws + ((size_t)4 << 20));      // 4 MB
    short* whpk  = (short*)((char*)d_ws + ((size_t)8 << 20));      // 128 KB
    float* dummy = (float*)((char*)d_ws + ((size_t)16 << 20));     // 4 MB ablation sink

    k_prep<<<32, 256, 0, stream>>>(wh_w, whpk);
    k_wc<<<1024, 64, 0, stream>>>(cur, wc_w, wc_b, wc_ws);
    k_main<0><<<4096, 256, 0, stream>>>(hist, wc_ws, whpk, wh_b, qt_w, qt_b, hsum);
    k_main<1><<<4096, 256, 0, stream>>>(hist, wc_ws, whpk, wh_b, qt_w, qt_b, dummy);
    k_wf<<<512, 64, 0, stream>>>(cur, hsum, wf_w, wf_b, (float*)d_out);
}

// Round 14
// 135.193 us; speedup vs baseline: 1.3775x; 1.3775x over previous
//
#include <hip/hip_runtime.h>
#include <hip/hip_bf16.h>

#define Hh 50

typedef __attribute__((ext_vector_type(8))) short bf16x8;
typedef __attribute__((ext_vector_type(4))) float f32x4;

static __device__ __forceinline__ short b16(float x) {
    return __builtin_bit_cast(short, __float2bfloat16(x));
}
// convert 8 contiguous f32 to a bf16x8 MFMA fragment
static __device__ __forceinline__ bf16x8 cvt8(const float* p) {
    f32x4 a = *(const f32x4*)p;
    f32x4 b = *(const f32x4*)(p + 4);
    bf16x8 r;
    r[0] = b16(a[0]); r[1] = b16(a[1]); r[2] = b16(a[2]); r[3] = b16(a[3]);
    r[4] = b16(b[0]); r[5] = b16(b[1]); r[6] = b16(b[2]); r[7] = b16(b[3]);
    return r;
}

// -------- Kernel 0: pack wh_w into 16x16x32 B-fragment order --------
// whpk[((p*8+ks)*64+l)*8+j] = bf16(wh_w[p*16+(l&15)][ks*32+(l>>4)*8+j])
__global__ __launch_bounds__(256) void k_prep(const float* __restrict__ w,
                                              short* __restrict__ o) {
    int t = (int)blockIdx.x * 256 + threadIdx.x;   // 0..8191
    int p  = t >> 9;
    int ks = (t >> 6) & 7;
    int l  = t & 63;
    int col = p * 16 + (l & 15);
    int k   = ks * 32 + (l >> 4) * 8;
    bf16x8 v = cvt8(w + (size_t)col * 256 + k);
    *(bf16x8*)(o + (size_t)t * 8) = v;
}

// ---------------- Kernel 1: wc_out[4096][256] (f32) = cur @ wc_w^T + wc_b ----------------
__global__ __launch_bounds__(64) void k_wc(const float* __restrict__ cur,
                                           const float* __restrict__ wcw,
                                           const float* __restrict__ wcb,
                                           float* __restrict__ out) {
    int l = threadIdx.x;
    int m0 = (int)(blockIdx.x >> 2) * 16;
    int ntb = (int)(blockIdx.x & 3) * 4;
    int lk = (l >> 4) * 8;

    bf16x8 Af[8];
#pragma unroll
    for (int k = 0; k < 8; k++)
        Af[k] = cvt8(cur + (size_t)(m0 + (l & 15)) * 256 + k * 32 + lk);

#pragma unroll
    for (int nt = 0; nt < 4; nt++) {
        int col = (ntb + nt) * 16 + (l & 15);
        f32x4 a = {0.f, 0.f, 0.f, 0.f};
#pragma unroll
        for (int k = 0; k < 8; k++) {
            bf16x8 Bf = cvt8(wcw + (size_t)col * 256 + k * 32 + lk);
            a = __builtin_amdgcn_mfma_f32_16x16x32_bf16(Af[k], Bf, a, 0, 0, 0);
        }
        float bias = wcb[col];
        int row = m0 + (l >> 4) * 4;
#pragma unroll
        for (int r = 0; r < 4; r++)
            out[(size_t)(row + r) * 256 + col] = a[r] + bias;
    }
}

// ---------------- Kernel 2: fused wh GEMM + sigmoid + qt dot + alpha*hist ----------------
// Block = (b, s), 256 thr = 4 waves. 16 independent MFMA chains per wave
// (acc[4m][4nt] -> 64 AGPRs). A (LDS) and B (global whpk) 2-deep double-buffered.
// launch_bounds(256, 3): total reg budget 170/wave -> ~106 arch VGPRs usable, so
// the 64-reg double-buffer CANNOT spill (r12's failure was the (256,4)=128-total cap).
__global__ __launch_bounds__(256, 3)
void k_main(const float* __restrict__ hist,
            const float* __restrict__ wc_ws,
            const short* __restrict__ whpk,
            const float* __restrict__ whb,
            const float* __restrict__ qtw,
            const float* __restrict__ qtb,
            float* __restrict__ hsum_ws) {
    __shared__ __align__(16) char histA[64 * 512];   // swizzled bf16 [row][256]
    __shared__ float wcrow[256];                     // wc_out[b,s,:] + wh_b
    __shared__ float qtl[256];
    __shared__ float alphaP[4][64];
    __shared__ float alphaF[64];

    int tid = threadIdx.x;
    int l = tid & 63;
    int w = tid >> 6;
    int b = (int)(blockIdx.x >> 9);
    int s = (int)(blockIdx.x & 511);

    // stage 50 hist rows (f32 -> bf16) into swizzled LDS
    for (int c = tid; c < 1600; c += 256) {
        int r = c >> 5, g = c & 31;
        bf16x8 v = cvt8(hist + ((size_t)(b * Hh + r) * 512 + s) * 256 + g * 8);
        *(bf16x8*)(&histA[r * 512 + ((g ^ (r & 15)) << 4)]) = v;
    }
    // zero pad rows 50..63
    if (tid < 448) {
        int r = 50 + (tid >> 5), g = tid & 31;
        *(f32x4*)(&histA[r * 512 + ((g ^ (r & 15)) << 4)]) = (f32x4){0.f, 0.f, 0.f, 0.f};
    }
    wcrow[tid] = wc_ws[(size_t)(b * 512 + s) * 256 + tid] + whb[tid];
    qtl[tid] = qtw[tid];
    __syncthreads();

    bf16x8 Ab[2][4], Bb[2][4];
    auto LDA = [&](bf16x8(&A)[4], int ks) {
#pragma unroll
        for (int m = 0; m < 4; m++) {
            int rA = m * 16 + (l & 15);
            int g = ks * 4 + (l >> 4);
            A[m] = *(const bf16x8*)(&histA[rA * 512 + ((g ^ (rA & 15)) << 4)]);
        }
    };
    auto LDB = [&](bf16x8(&Bf)[4], int ks) {
#pragma unroll
        for (int nt = 0; nt < 4; nt++) {
            int p = w * 4 + nt;
            Bf[nt] = *(const bf16x8*)(whpk + ((size_t)((p * 8 + ks) * 64 + l)) * 8);
        }
    };

    f32x4 acc[4][4];
#pragma unroll
    for (int m = 0; m < 4; m++)
#pragma unroll
        for (int nt = 0; nt < 4; nt++)
            acc[m][nt] = (f32x4){0.f, 0.f, 0.f, 0.f};

    LDB(Bb[0], 0);
    LDA(Ab[0], 0);
#pragma unroll
    for (int ks = 0; ks < 8; ks++) {
        int cur = ks & 1, nxt = cur ^ 1;
        if (ks < 7) {
            LDB(Bb[nxt], ks + 1);
            LDA(Ab[nxt], ks + 1);
        }
#pragma unroll
        for (int m = 0; m < 4; m++)
#pragma unroll
            for (int nt = 0; nt < 4; nt++)
                acc[m][nt] = __builtin_amdgcn_mfma_f32_16x16x32_bf16(
                    Ab[cur][m], Bb[cur][nt], acc[m][nt], 0, 0, 0);
    }

    // ---- epilogue: sigmoid + qt, per-lane partial over this wave's 64 cols ----
    float pal[4][4];
#pragma unroll
    for (int m = 0; m < 4; m++)
#pragma unroll
        for (int r = 0; r < 4; r++) pal[m][r] = 0.f;

#pragma unroll
    for (int m = 0; m < 4; m++) {
#pragma unroll
        for (int nt = 0; nt < 4; nt++) {
            int col = w * 64 + nt * 16 + (l & 15);
            float qv = qtl[col], wb = wcrow[col];
#pragma unroll
            for (int r = 0; r < 4; r++) {
                float v = acc[m][nt][r] + wb;
                pal[m][r] += qv * __builtin_amdgcn_rcpf(1.0f + __expf(-v));
            }
        }
    }

    // reduce over the 16 lanes holding the 16 cols of each tile
#pragma unroll
    for (int m = 0; m < 4; m++) {
#pragma unroll
        for (int r = 0; r < 4; r++) {
            float v = pal[m][r];
            v += __shfl_xor(v, 1);
            v += __shfl_xor(v, 2);
            v += __shfl_xor(v, 4);
            v += __shfl_xor(v, 8);
            if ((l & 15) == 0)
                alphaP[w][m * 16 + (l >> 4) * 4 + r] = v;
        }
    }
    __syncthreads();
    if (tid < Hh)
        alphaF[tid] = qtb[0] + alphaP[0][tid] + alphaP[1][tid] + alphaP[2][tid] + alphaP[3][tid];
    __syncthreads();

    // history_sum = sum_h alpha[h] * hist[h], from LDS; one f32 column/thread
    {
        int d = tid;
        float a = 0.f;
#pragma unroll 2
        for (int h = 0; h < Hh; h++) {
            int g = (d >> 3) ^ (h & 15);
            unsigned short u = *(const unsigned short*)(&histA[h * 512 + (g << 4) + (d & 7) * 2]);
            unsigned int x = ((unsigned int)u) << 16;
            a += alphaF[h] * __builtin_bit_cast(float, x);
        }
        hsum_ws[(size_t)(b * 512 + s) * 256 + d] = a;
    }
}

// ---------------- Kernel 3: out[4096][128] (f32) = [cur, hsum] @ wf_w^T + wf_b ----------------
__global__ __launch_bounds__(64) void k_wf(const float* __restrict__ cur,
                                           const float* __restrict__ hsum,
                                           const float* __restrict__ wfw,
                                           const float* __restrict__ wfb,
                                           float* __restrict__ out) {
    int l = threadIdx.x;
    int m0 = (int)(blockIdx.x >> 1) * 16;
    int ntb = (int)(blockIdx.x & 1) * 4;
    int lk = (l >> 4) * 8;

    f32x4 acc[4];
#pragma unroll
    for (int nt = 0; nt < 4; nt++) acc[nt] = (f32x4){0.f, 0.f, 0.f, 0.f};

#pragma unroll
    for (int k = 0; k < 16; k++) {
        int row = m0 + (l & 15);
        bf16x8 Af;
        if (k < 8)
            Af = cvt8(cur + (size_t)row * 256 + k * 32 + lk);
        else
            Af = cvt8(hsum + (size_t)row * 256 + (k - 8) * 32 + lk);
#pragma unroll
        for (int nt = 0; nt < 4; nt++) {
            int col = (ntb + nt) * 16 + (l & 15);
            bf16x8 Bf = cvt8(wfw + (size_t)col * 512 + k * 32 + lk);
            acc[nt] = __builtin_amdgcn_mfma_f32_16x16x32_bf16(Af, Bf, acc[nt], 0, 0, 0);
        }
    }
#pragma unroll
    for (int nt = 0; nt < 4; nt++) {
        int col = (ntb + nt) * 16 + (l & 15);
        float bias = wfb[col];
        int row = m0 + (l >> 4) * 4;
#pragma unroll
        for (int r = 0; r < 4; r++)
            out[(size_t)(row + r) * 128 + col] = acc[nt][r] + bias;
    }
}

extern "C" void kernel_launch(void* const* d_in, const int* in_sizes, int n_in,
                              void* d_out, int out_size, void* d_ws, size_t ws_size,
                              hipStream_t stream) {
    const float* hist = (const float*)d_in[0];
    const float* cur  = (const float*)d_in[1];
    const float* wc_w = (const float*)d_in[2];
    const float* wc_b = (const float*)d_in[3];
    const float* wh_w = (const float*)d_in[4];
    const float* wh_b = (const float*)d_in[5];
    const float* qt_w = (const float*)d_in[6];
    const float* qt_b = (const float*)d_in[7];
    const float* wf_w = (const float*)d_in[8];
    const float* wf_b = (const float*)d_in[9];

    float* wc_ws = (float*)d_ws;                                   // 4 MB
    float* hsum  = (float*)((char*)d_ws + ((size_t)4 << 20));      // 4 MB
    short* whpk  = (short*)((char*)d_ws + ((size_t)8 << 20));      // 128 KB

    k_prep<<<32, 256, 0, stream>>>(wh_w, whpk);
    k_wc<<<1024, 64, 0, stream>>>(cur, wc_w, wc_b, wc_ws);
    k_main<<<4096, 256, 0, stream>>>(hist, wc_ws, whpk, wh_b, qt_w, qt_b, hsum);
    k_wf<<<512, 64, 0, stream>>>(cur, hsum, wf_w, wf_b, (float*)d_out);
}